// Round 5
// baseline (620.862 us; speedup 1.0000x reference)
//
#include <hip/hip_runtime.h>

#define RNN_B 256
#define RNN_T 2048
#define RNN_IN 64
#define RNN_N 32
#define RNN_O 32
#define RNN_R 6
#define RNN_ALPHA 0.1f
#define KSCALE 2.8853900817779268f   /* 2*log2(e): folded into cm and xp */

// ---------------------------------------------------------------------------
// Kernel 1: xp[b][t][n] = KSCALE * (bias[n] + sum_i W_in[n][i] * u[b][t][i])
// ---------------------------------------------------------------------------
__global__ __launch_bounds__(256) void k_xproj(
    const float* __restrict__ u, const float* __restrict__ W_in,
    const float* __restrict__ bias, float* __restrict__ xp)
{
    const int tid = blockIdx.x * 256 + threadIdx.x;   // = b*T + t
    const float4* __restrict__ u4 =
        reinterpret_cast<const float4*>(u) + (size_t)tid * (RNN_IN / 4);
    float acc[RNN_N];
    #pragma unroll
    for (int n = 0; n < RNN_N; ++n) acc[n] = bias[n];
    #pragma unroll
    for (int q = 0; q < RNN_IN / 4; ++q) {
        const float4 v = u4[q];
        #pragma unroll
        for (int n = 0; n < RNN_N; ++n) {
            const float* wr = W_in + n * RNN_IN + 4 * q;   // uniform -> s_load
            acc[n] = fmaf(wr[0], v.x, acc[n]);
            acc[n] = fmaf(wr[1], v.y, acc[n]);
            acc[n] = fmaf(wr[2], v.z, acc[n]);
            acc[n] = fmaf(wr[3], v.w, acc[n]);
        }
    }
    float4* __restrict__ o4 =
        reinterpret_cast<float4*>(xp) + (size_t)tid * (RNN_N / 4);
    #pragma unroll
    for (int q = 0; q < RNN_N / 4; ++q)
        o4[q] = make_float4(KSCALE * acc[4*q+0], KSCALE * acc[4*q+1],
                            KSCALE * acc[4*q+2], KSCALE * acc[4*q+3]);
}

// ---------------------------------------------------------------------------
// Row-local (16-lane) all-reduce stages: VALU DPP (builtin path -> compiler
// handles DPP read-after-VALU hazards; GCNDPPCombine may fuse mov+add).
// ---------------------------------------------------------------------------
template <int CTRL>
__device__ __forceinline__ float dpp_add(float v) {
    int t = __builtin_amdgcn_update_dpp(0, __float_as_int(v), CTRL, 0xf, 0xf, true);
    return v + __int_as_float(t);
}
__device__ __forceinline__ float sum16(float v) {
    v = dpp_add<0xB1>(v);    // quad_perm [1,0,3,2] : xor1
    v = dpp_add<0x4E>(v);    // quad_perm [2,3,0,1] : xor2
    v = dpp_add<0x141>(v);   // row_half_mirror     : cross-quad within 8
    v = dpp_add<0x140>(v);   // row_mirror          : cross-8 within 16
    return v;
}

// v[i] + v[i^32] in every lane: one permlane32_swap (both outputs used) + add.
// Orientation-independent: r.x + r.y == v[i] + v[i^32] either way.
__device__ __forceinline__ float xsum32(float v) {
#if __has_builtin(__builtin_amdgcn_permlane32_swap)
    typedef int v2i __attribute__((ext_vector_type(2)));
    v2i r = __builtin_amdgcn_permlane32_swap(__float_as_int(v),
                                             __float_as_int(v), false, false);
    return __int_as_float(r.x) + __int_as_float(r.y);
#else
    return v + __shfl_xor(v, 32, 64);
#endif
}
// v[i] + v[i^16] in every lane (same trick with permlane16_swap).
__device__ __forceinline__ float xsum16(float v) {
#if __has_builtin(__builtin_amdgcn_permlane16_swap)
    typedef int v2i __attribute__((ext_vector_type(2)));
    v2i r = __builtin_amdgcn_permlane16_swap(__float_as_int(v),
                                             __float_as_int(v), false, false);
    return __int_as_float(r.x) + __int_as_float(r.y);
#else
    return v + __shfl_xor(v, 16, 64);
#endif
}

__device__ __forceinline__ float fast_exp2(float x) {
#if __has_builtin(__builtin_amdgcn_exp2f)
    return __builtin_amdgcn_exp2f(x);
#else
    return __expf(x * 0.6931471805599453f);
#endif
}
__device__ __forceinline__ float fast_rcp(float x) {
#if __has_builtin(__builtin_amdgcn_rcpf)
    return __builtin_amdgcn_rcpf(x);
#else
    return __frcp_rn(x);
#endif
}

// ---------------------------------------------------------------------------
// Kernel 2: sequential scan, one wave per batch. 2x2 lane decomposition:
//   k = lane&15, q = (lane>>4)&1 (rank group), p = lane>>5 (element parity).
// Each lane owns ONE hidden element e = 2k+p (replicated across the 2 rank
// groups) and FOUR rank slots r = 4q+j (r==7 is a zero pad).
// Per step:
//   prod_j = cn[j]*h                      (4 mul)
//   tree over 16 k-lanes                  (4 DPP chains x 4 stages)
//     -> S_r^(parity p)
//   S_r = xsum32(.)                       (parity combine, 4x swap+add)
//   w   = sum_j cm[j]*S_j                 (rank fold for MY element, 5 ops)
//   w  += partner (lane^16, same element, other ranks) via xsum16
//   z   = w + xe ; h' = (0.9h+0.1) - 0.2*rcp(exp2(z)+1)   (ONE tanh chain)
// Store: lanes with q==0 (32 lanes, all 32 elements) scalar-store h -> one
// 128B segment per step. All cross-lane ops are VALU permlane/DPP; no LDS.
// ---------------------------------------------------------------------------
__global__ __launch_bounds__(64, 1) void k_recur(
    const float* __restrict__ m, const float* __restrict__ nvec,
    const float* __restrict__ Mmat, const float* __restrict__ Nmat,
    const float* __restrict__ xp,    // [B,T,N] prescaled input projections
    float* __restrict__ hout,        // [B,T,N] hidden states (ws or out)
    float* __restrict__ hfin)
{
    const int b    = blockIdx.x;
    const int lane = threadIdx.x;
    const int k    = lane & 15;
    const int q    = (lane >> 4) & 1;    // rank group: 0 -> r 0..3, 1 -> r 4..6
    const int p    = lane >> 5;          // element parity
    const int e    = 2 * k + p;          // my hidden element

    // Per-lane coefficients for my 4 rank slots (r = 4q+j; r==0 -> m/n,
    // 1..6 -> cols of M/N, 7 -> zero pad). cm prescaled by 2*log2(e).
    float cn[4], cm[4];
    #pragma unroll
    for (int j = 0; j < 4; ++j) {
        const int r = 4 * q + j;
        float cnv = 0.f, cmv = 0.f;
        if (r == 0)      { cnv = nvec[e];              cmv = m[e]; }
        else if (r <= RNN_R) { cnv = Nmat[e*RNN_R + (r-1)]; cmv = Mmat[e*RNN_R + (r-1)]; }
        cn[j] = cnv;
        cm[j] = KSCALE * cmv;
    }

    const float2* __restrict__ x2 =
        reinterpret_cast<const float2*>(xp + (size_t)b * (RNN_T * RNN_N)) + k;
    float* __restrict__ hbase = hout + (size_t)b * (RNN_T * RNN_N);

    float h = 0.0f;

    const int PF = 8;                    // prefetch ring, static t&7 indexing
    float2 xr[PF];
    #pragma unroll
    for (int i = 0; i < PF; ++i) xr[i] = x2[i * (RNN_N / 2)];

    const bool do_store = (q == 0);      // 32 lanes cover all 32 elements

    #pragma unroll 8
    for (int t = 0; t < RNN_T; ++t) {
        const int slot = t & (PF - 1);   // compile-time const per unrolled body
        const float2 xv = xr[slot];
        // Unconditional prefetch (past-T reads land in the hfin tail region
        // of the same allocation; values unused).
        xr[slot] = x2[(t + PF) * (RNN_N / 2)];
        const float xe = p ? xv.y : xv.x;

        // 4 products + 4 interleaved 16-lane DPP trees.
        float s0 = cn[0] * h, s1 = cn[1] * h, s2 = cn[2] * h, s3 = cn[3] * h;
        s0 = dpp_add<0xB1>(s0);  s1 = dpp_add<0xB1>(s1);
        s2 = dpp_add<0xB1>(s2);  s3 = dpp_add<0xB1>(s3);
        s0 = dpp_add<0x4E>(s0);  s1 = dpp_add<0x4E>(s1);
        s2 = dpp_add<0x4E>(s2);  s3 = dpp_add<0x4E>(s3);
        s0 = dpp_add<0x141>(s0); s1 = dpp_add<0x141>(s1);
        s2 = dpp_add<0x141>(s2); s3 = dpp_add<0x141>(s3);
        s0 = dpp_add<0x140>(s0); s1 = dpp_add<0x140>(s1);
        s2 = dpp_add<0x140>(s2); s3 = dpp_add<0x140>(s3);

        // Parity combine: full 32-element rank sums.
        s0 = xsum32(s0); s1 = xsum32(s1); s2 = xsum32(s2); s3 = xsum32(s3);

        // Rank fold for my element, then rank-group combine (lane^16 partner
        // has the SAME element and the other 3-4 ranks).
        float w = fmaf(cm[1], s1, cm[0] * s0) + fmaf(cm[3], s3, cm[2] * s2);
        w = xsum16(w);
        const float z = w + xe;

        // tanh via exp2: h' = (0.9h + 0.1) - 0.2*rcp(exp2(z)+1)
        const float ez = fast_exp2(z);
        const float g  = fmaf(1.0f - RNN_ALPHA, h, RNN_ALPHA);
        h = fmaf(-2.0f * RNN_ALPHA, fast_rcp(ez + 1.0f), g);

        // 32 active lanes write all 32 elements: one 128B segment.
        if (do_store) hbase[t * RNN_N + e] = h;
    }
    if (do_store) hfin[b * RNN_N + e] = h;
}

// ---------------------------------------------------------------------------
// Kernel 3: output projection, separate src (h) / dst (y) streams.
// ---------------------------------------------------------------------------
__global__ __launch_bounds__(256) void k_out(
    const float* __restrict__ W_out, const float* __restrict__ b_out,
    const float* __restrict__ hsrc, float* __restrict__ ydst)
{
    const int tid = blockIdx.x * 256 + threadIdx.x;   // = b*T + t
    const float4* __restrict__ p4 =
        reinterpret_cast<const float4*>(hsrc) + (size_t)tid * (RNN_N / 4);
    float4* __restrict__ q4 =
        reinterpret_cast<float4*>(ydst) + (size_t)tid * (RNN_N / 4);
    float y[RNN_O];
    #pragma unroll
    for (int o = 0; o < RNN_O; ++o) y[o] = b_out[o];
    #pragma unroll
    for (int q = 0; q < RNN_N / 4; ++q) {
        const float4 v = p4[q];
        #pragma unroll
        for (int o = 0; o < RNN_O; ++o) {
            const float* wr = W_out + o * RNN_N + 4 * q;  // uniform -> s_load
            y[o] = fmaf(wr[0], v.x, y[o]);
            y[o] = fmaf(wr[1], v.y, y[o]);
            y[o] = fmaf(wr[2], v.z, y[o]);
            y[o] = fmaf(wr[3], v.w, y[o]);
        }
    }
    #pragma unroll
    for (int q = 0; q < RNN_N / 4; ++q)
        q4[q] = make_float4(y[4*q+0], y[4*q+1], y[4*q+2], y[4*q+3]);
}

extern "C" void kernel_launch(void* const* d_in, const int* in_sizes, int n_in,
                              void* d_out, int out_size, void* d_ws, size_t ws_size,
                              hipStream_t stream)
{
    const float* u     = (const float*)d_in[0];  // [256,2048,64]
    const float* W_in  = (const float*)d_in[1];  // [32,64]
    const float* m     = (const float*)d_in[2];  // [32,1]
    const float* nvec  = (const float*)d_in[3];  // [32,1]
    const float* Mmat  = (const float*)d_in[4];  // [32,6]
    const float* Nmat  = (const float*)d_in[5];  // [32,6]
    const float* bias  = (const float*)d_in[6];  // [32]
    const float* W_out = (const float*)d_in[7];  // [32,32]
    const float* b_out = (const float*)d_in[8];  // [32]
    float* out = (float*)d_out;                  // outputs [256,2048,32] ++ h_final [256,32]

    float* hfin = out + (size_t)RNN_B * RNN_T * RNN_N;

    // h states routed through the workspace so k_recur's loads (xp, from out)
    // and stores (h, to ws) are provably non-aliasing. Fallback: in-place.
    const size_t hbytes = (size_t)RNN_B * RNN_T * RNN_N * sizeof(float);
    float* hbuf = (ws_size >= hbytes) ? (float*)d_ws : out;

    k_xproj<<<(RNN_B * RNN_T) / 256, 256, 0, stream>>>(u, W_in, bias, out);
    k_recur<<<RNN_B, 64, 0, stream>>>(m, nvec, Mmat, Nmat, out, hbuf, hfin);
    k_out  <<<(RNN_B * RNN_T) / 256, 256, 0, stream>>>(W_out, b_out, hbuf, out);
}